// Round 9
// baseline (299.391 us; speedup 1.0000x reference)
//
#include <hip/hip_runtime.h>
#include <hip/hip_bf16.h>

// Round 9: GEMMs go barrier-free — MFMA fragments loaded DIRECTLY from global
// (one dwordx4 per lane per fragment; K-contiguous in the B^T layout), no LDS,
// no __syncthreads in the K-loop. Each wave = independent 64x64 tile stream with
// depth-2 register prefetch. Rationale: r5-r8 showed the LDS+barrier K-loop is
// pinned at ~80 µs by the per-block serial chain, not by MFMA/VALU/HBM.
// Attention/pack/cvt unchanged from round 8.
//
// ws layout:
//   [A] qkv_b16: 3072*3840 bf16 (23.6 MB)
//   [B] hs_b   : 3072*1280 bf16 (7.9 MB)  -- reused as attn_b after gemm1
//   [C] qkvw_b : 3840*1280 bf16 (9.8 MB)  -- reused as Qp after gemm1
//   [D] projw_b: 1280*1280 bf16 (3.3 MB)
//   [E] Kp     : 3*16*16*6144 bf16 (9.4 MB)
//   [F] Vp     : 3*16*16*6144 bf16 (9.4 MB)  (96-wide, col80 = ones)

#define S_TOT 3072
#define DIM   1280
#define NH    16
#define HD    80
#define SEG   1024
#define TDIM  3840

typedef short v8s __attribute__((ext_vector_type(8)));
typedef float v4f __attribute__((ext_vector_type(4)));

__device__ __forceinline__ short f2bf(float v) {
  __hip_bfloat16 b = __float2bfloat16(v);
  return *reinterpret_cast<short*>(&b);
}

__device__ __forceinline__ float bf2f(short s) {
  unsigned u = ((unsigned)(unsigned short)s) << 16;
  float f;
  __builtin_memcpy(&f, &u, 4);
  return f;
}

// fused fp32->bf16 for hs / qkv_w / proj_w (one launch)
#define CVT_N1 (S_TOT * DIM / 4)
#define CVT_N2 (TDIM * DIM / 4)
#define CVT_N3 (DIM * DIM / 4)
__global__ __launch_bounds__(256) void cvt3(const float* __restrict__ in1,
                                            const float* __restrict__ in2,
                                            const float* __restrict__ in3,
                                            __hip_bfloat16* __restrict__ o1,
                                            __hip_bfloat16* __restrict__ o2,
                                            __hip_bfloat16* __restrict__ o3) {
  int i = blockIdx.x * 256 + threadIdx.x;
  const float* in;
  __hip_bfloat16* out;
  if (i < CVT_N1) { in = in1; out = o1; }
  else if (i < CVT_N1 + CVT_N2) { in = in2; out = o2; i -= CVT_N1; }
  else { in = in3; out = o3; i -= CVT_N1 + CVT_N2; }
  const float4 v = ((const float4*)in)[i];
  __hip_bfloat162 p0, p1;
  p0.x = __float2bfloat16(v.x); p0.y = __float2bfloat16(v.y);
  p1.x = __float2bfloat16(v.z); p1.y = __float2bfloat16(v.w);
  __hip_bfloat162* o = (__hip_bfloat162*)(out + (size_t)i * 4);
  o[0] = p0; o[1] = p1;
}

// ---------------- direct-from-global GEMM, no LDS, no barriers ----------------
// C[M,N] = A[M,K] @ B[N,K]^T + bias[N]. Block = 4 independent waves, each owning
// a 64x64 tile of the block's 128x128 region. Fragment = dwordx4/lane from global.
// grid (N/128, M/128); K % 64 == 0.
template <bool OUT_BF16>
__global__ __launch_bounds__(256, 3) void gemm_direct(const __hip_bfloat16* __restrict__ A,
                                                      const __hip_bfloat16* __restrict__ B,
                                                      const float* __restrict__ bias,
                                                      void* __restrict__ Cout,
                                                      int M, int N, int K) {
  const int tid  = threadIdx.x;
  const int wave = tid >> 6;
  const int lane = tid & 63;
  const int quad = lane >> 4;   // k-half selector for loads; row-quad for C
  const int l16  = lane & 15;
  const int rm = blockIdx.y * 128 + (wave >> 1) * 64;
  const int cn = blockIdx.x * 128 + (wave & 1) * 64;

  // per-fragment lane base addresses (row = tile + i*16 + l16, k = quad*8)
  const __hip_bfloat16* Ab[4];
  const __hip_bfloat16* Bb[4];
  #pragma unroll
  for (int i = 0; i < 4; ++i) {
    Ab[i] = A + (size_t)(rm + i * 16 + l16) * K + quad * 8;
    Bb[i] = B + (size_t)(cn + i * 16 + l16) * K + quad * 8;
  }

  v4f acc[4][4];
  const v4f vz = {0.f, 0.f, 0.f, 0.f};
  #pragma unroll
  for (int i = 0; i < 4; ++i)
    #pragma unroll
    for (int j = 0; j < 4; ++j) acc[i][j] = vz;

  const int nk = K >> 5;  // BK=32 slabs
  v8s fa[2][4], fb[2][4];

  // prologue: slabs 0,1 in flight
  #pragma unroll
  for (int s = 0; s < 2; ++s)
    #pragma unroll
    for (int i = 0; i < 4; ++i) {
      fa[s][i] = *(const v8s*)(Ab[i] + s * 32);
      fb[s][i] = *(const v8s*)(Bb[i] + s * 32);
    }

  for (int k = 0; k < nk; k += 2) {
    // compute slab k (set 0), then refill set 0 with slab k+2
    #pragma unroll
    for (int i = 0; i < 4; ++i)
      #pragma unroll
      for (int j = 0; j < 4; ++j)
        acc[i][j] = __builtin_amdgcn_mfma_f32_16x16x32_bf16(fa[0][i], fb[0][j],
                                                            acc[i][j], 0, 0, 0);
    if (k + 2 < nk) {
      const int off = (k + 2) * 32;
      #pragma unroll
      for (int i = 0; i < 4; ++i) {
        fa[0][i] = *(const v8s*)(Ab[i] + off);
        fb[0][i] = *(const v8s*)(Bb[i] + off);
      }
    }
    // compute slab k+1 (set 1), then refill set 1 with slab k+3
    #pragma unroll
    for (int i = 0; i < 4; ++i)
      #pragma unroll
      for (int j = 0; j < 4; ++j)
        acc[i][j] = __builtin_amdgcn_mfma_f32_16x16x32_bf16(fa[1][i], fb[1][j],
                                                            acc[i][j], 0, 0, 0);
    if (k + 3 < nk) {
      const int off = (k + 3) * 32;
      #pragma unroll
      for (int i = 0; i < 4; ++i) {
        fa[1][i] = *(const v8s*)(Ab[i] + off);
        fb[1][i] = *(const v8s*)(Bb[i] + off);
      }
    }
  }

  #pragma unroll
  for (int j = 0; j < 4; ++j) {
    const int col = cn + j * 16 + l16;
    const float bj = bias[col];
    #pragma unroll
    for (int i = 0; i < 4; ++i) {
      const int row0 = rm + i * 16 + quad * 4;
      #pragma unroll
      for (int r = 0; r < 4; ++r) {
        const float v = acc[i][j][r] + bj;
        if (OUT_BF16)
          ((__hip_bfloat16*)Cout)[(size_t)(row0 + r) * N + col] = __float2bfloat16(v);
        else
          ((float*)Cout)[(size_t)(row0 + r) * N + col] = v;
      }
    }
  }
}

// ---------------- merged pack kernel (unchanged from round 8) ----------------
#define QK_BLOCKS ((2 * S_TOT * 16 * 12) / 256)   // 4608
#define V_BLOCKS  ((3 * 16 * 16 * 8 * 96) / 256)  // 2304
__global__ __launch_bounds__(256) void pack_all(const __hip_bfloat16* __restrict__ qkv,
                                                const float* __restrict__ cos_,
                                                const float* __restrict__ sin_,
                                                short* __restrict__ Qp,
                                                short* __restrict__ Kp,
                                                short* __restrict__ Vp) {
  const int bid = blockIdx.x;
  if (bid < QK_BLOCKS) {
    const int idx = bid * 256 + threadIdx.x;
    const int kd = idx % 12;
    const int h  = (idx / 12) % 16;
    const int s  = (idx / 192) % S_TOT;
    const int p  = idx / (192 * S_TOT);
    const int seg = s >> 10, tb = (s >> 6) & 15, t = s & 63;
    short* out = (p ? Kp : Qp) +
                 ((size_t)(((seg * 16 + h) * 16 + tb) * 12 + kd) * 64 + t) * 8;
    short tmp[8];
    if (kd >= 10) {
      #pragma unroll
      for (int j = 0; j < 8; ++j) tmp[j] = 0;
      *(int4*)out = *(int4*)tmp;
      return;
    }
    const short* row = (const short*)qkv + (size_t)s * TDIM + p * DIM + h * HD;
    const int d0 = kd * 8;
    const v8s xm = *(const v8s*)(row + d0);
    const v8s xr = *(const v8s*)(row + d0 + ((kd < 5) ? 40 : -40));
    const float sgn = (kd < 5) ? -1.f : 1.f;
    const float scale = (p == 0) ? 0.111803398874989485f : 1.0f;
    #pragma unroll
    for (int j = 0; j < 8; ++j) {
      const int d = d0 + j;
      const float v = (bf2f(xm[j]) * cos_[s * HD + d] +
                       sgn * bf2f(xr[j]) * sin_[s * HD + d]) * scale;
      tmp[j] = f2bf(v);
    }
    *(int4*)out = *(int4*)tmp;
  } else {
    const int idx = (bid - QK_BLOCKS) * 256 + threadIdx.x;
    const int d  = idx % 96;
    const int td = (idx / 96) % 8;
    const int tb = (idx / 768) % 16;
    const int h  = (idx / (768 * 16)) % 16;
    const int seg = idx / (768 * 256);
    const int s0 = seg * SEG + tb * 64 + td * 8;
    const short* q = (const short*)qkv;
    short tmp[8];
    if (d < 80) {
      #pragma unroll
      for (int j = 0; j < 8; ++j)
        tmp[j] = q[(size_t)(s0 + j) * TDIM + 2 * DIM + h * HD + d];
    } else {
      const short fill = (d == 80) ? (short)0x3F80 : (short)0;
      #pragma unroll
      for (int j = 0; j < 8; ++j) tmp[j] = fill;
    }
    *(int4*)(Vp + (size_t)idx * 8) = *(int4*)tmp;
  }
}

// ---------------- flash MFMA attention (unchanged from round 8) ----------------
__global__ __launch_bounds__(256, 3) void attn_mfma(const short* __restrict__ Qp,
                                                    const short* __restrict__ Kp,
                                                    const short* __restrict__ Vp,
                                                    __hip_bfloat16* __restrict__ out) {
  __shared__ __align__(16) short Qs[64 * 96];     // 12 KB
  __shared__ __align__(16) short Ks[64 * 96];     // 12 KB
  __shared__ __align__(16) short Vs[64 * 96];     // 12 KB
  __shared__ __align__(16) short Ps[4][16 * 68];  // 8.5 KB, wave-private

  const int qt  = blockIdx.x;
  const int h   = blockIdx.y;
  const int seg = blockIdx.z;
  const int tid  = threadIdx.x;
  const int wave = tid >> 6;
  const int lane = tid & 63;
  const int quad = lane >> 4;
  const int l16  = lane & 15;
  const int sh16 = seg * 16 + h;

  const short* Qg = Qp + (size_t)(sh16 * 16 + qt) * 6144;
  const short* Kg = Kp + (size_t)sh16 * 16 * 6144;
  const short* Vg = Vp + (size_t)sh16 * 16 * 6144;

  v8s qr[3], kr[3], vr[3];
  #pragma unroll
  for (int it = 0; it < 3; ++it) {
    const int o = (it * 256 + tid) * 8;
    qr[it] = *(const v8s*)(Qg + o);
    kr[it] = *(const v8s*)(Kg + o);
    vr[it] = *(const v8s*)(Vg + o);
  }
  #pragma unroll
  for (int it = 0; it < 3; ++it) {
    const int o = (it * 256 + tid) * 8;
    *(v8s*)&Qs[o] = qr[it];
    *(v8s*)&Ks[o] = kr[it];
    *(v8s*)&Vs[o] = vr[it];
  }
  __syncthreads();

  v8s af[3];
  #pragma unroll
  for (int ks = 0; ks < 3; ++ks)
    af[ks] = *(const v8s*)&Qs[((ks * 4 + quad) * 64 + wave * 16 + l16) * 8];

  v4f o4[6];
  const v4f vz = {0.f, 0.f, 0.f, 0.f};
  #pragma unroll
  for (int n = 0; n < 6; ++n) o4[n] = vz;

  for (int kb = 0; kb < 16; ++kb) {
    const bool more = (kb + 1 < 16);
    if (more) {
      const size_t base = (size_t)(kb + 1) * 6144;
      #pragma unroll
      for (int it = 0; it < 3; ++it) {
        const int o = (it * 256 + tid) * 8;
        kr[it] = *(const v8s*)(Kg + base + o);
        vr[it] = *(const v8s*)(Vg + base + o);
      }
    }

    v4f s4[4];
    #pragma unroll
    for (int j = 0; j < 4; ++j) {
      s4[j] = vz;
      #pragma unroll
      for (int ks = 0; ks < 3; ++ks) {
        const v8s bf = *(const v8s*)&Ks[((ks * 4 + quad) * 64 + j * 16 + l16) * 8];
        s4[j] = __builtin_amdgcn_mfma_f32_16x16x32_bf16(af[ks], bf, s4[j], 0, 0, 0);
      }
    }

    #pragma unroll
    for (int reg = 0; reg < 4; ++reg)
      #pragma unroll
      for (int j = 0; j < 4; ++j)
        Ps[wave][(quad * 4 + reg) * 68 + j * 16 + l16] = f2bf(__expf(s4[j][reg]));

    v8s pa[2];
    #pragma unroll
    for (int kp = 0; kp < 2; ++kp)
      pa[kp] = *(const v8s*)&Ps[wave][l16 * 68 + kp * 32 + quad * 8];
    #pragma unroll
    for (int n = 0; n < 6; ++n) {
      #pragma unroll
      for (int kp = 0; kp < 2; ++kp) {
        const v8s vb = *(const v8s*)&Vs[((kp * 4 + quad) * 96 + n * 16 + l16) * 8];
        o4[n] = __builtin_amdgcn_mfma_f32_16x16x32_bf16(pa[kp], vb, o4[n], 0, 0, 0);
      }
    }

    __syncthreads();
    if (more) {
      #pragma unroll
      for (int it = 0; it < 3; ++it) {
        const int o = (it * 256 + tid) * 8;
        *(v8s*)&Ks[o] = kr[it];
        *(v8s*)&Vs[o] = vr[it];
      }
    }
    __syncthreads();
  }

  float inv[4];
  #pragma unroll
  for (int r = 0; r < 4; ++r)
    inv[r] = 1.f / __shfl(o4[5][r], quad << 4);
  const int row0 = seg * SEG + qt * 64 + wave * 16 + quad * 4;
  #pragma unroll
  for (int n = 0; n < 5; ++n) {
    const int col = h * HD + n * 16 + l16;
    #pragma unroll
    for (int r = 0; r < 4; ++r)
      out[(size_t)(row0 + r) * DIM + col] = __float2bfloat16(o4[n][r] * inv[r]);
  }
}

extern "C" void kernel_launch(void* const* d_in, const int* in_sizes, int n_in,
                              void* d_out, int out_size, void* d_ws, size_t ws_size,
                              hipStream_t stream) {
  (void)in_sizes; (void)n_in; (void)out_size; (void)ws_size;
  const float* hs     = (const float*)d_in[0];
  const float* cosp   = (const float*)d_in[1];
  const float* sinp   = (const float*)d_in[2];
  const float* qkv_w  = (const float*)d_in[3];
  const float* qkv_b  = (const float*)d_in[4];
  const float* proj_w = (const float*)d_in[5];
  const float* proj_b = (const float*)d_in[6];

  float* out_f = (float*)d_out;
  __hip_bfloat16* qkv_b16 = (__hip_bfloat16*)d_ws;                     // [A]
  __hip_bfloat16* hs_b    = qkv_b16 + (size_t)S_TOT * TDIM;            // [B]
  __hip_bfloat16* qkvw_b  = hs_b + (size_t)S_TOT * DIM;                // [C]
  __hip_bfloat16* projw_b = qkvw_b + (size_t)TDIM * DIM;               // [D]
  short* Qp = (short*)qkvw_b;                                          // alias [C]
  short* Kp = (short*)(projw_b + (size_t)DIM * DIM);                   // [E]
  short* Vp = Kp + (size_t)3 * 16 * 16 * 6144;                         // [F]
  __hip_bfloat16* attn_b = hs_b;                                       // alias [B]

  cvt3<<<(CVT_N1 + CVT_N2 + CVT_N3) / 256, 256, 0, stream>>>(
      hs, qkv_w, proj_w, hs_b, qkvw_b, projw_b);

  gemm_direct<true><<<dim3(TDIM / 128, S_TOT / 128), 256, 0, stream>>>(
      hs_b, qkvw_b, qkv_b, (void*)qkv_b16, S_TOT, TDIM, DIM);

  pack_all<<<QK_BLOCKS + V_BLOCKS, 256, 0, stream>>>(qkv_b16, cosp, sinp, Qp, Kp, Vp);

  attn_mfma<<<dim3(16, NH, 3), 256, 0, stream>>>(Qp, Kp, Vp, attn_b);

  gemm_direct<false><<<dim3(DIM / 128, S_TOT / 128), 256, 0, stream>>>(
      attn_b, projw_b, proj_b, (void*)out_f, S_TOT, DIM, DIM);
}

// Round 10
// 255.229 us; speedup vs baseline: 1.1730x; 1.1730x over previous
//
#include <hip/hip_runtime.h>
#include <hip/hip_bf16.h>

// Round 10: L2/L3-aware grid ordering for both GEMMs. r6-exact K-loop (depth-1
// reg prefetch, one barrier/slab) but grid swapped so consecutive blocks (-> all
// 8 XCDs) share the SAME B column-tile: B is fetched from HBM once into L3 and
// hit by the other XCDs, instead of thrashing per-XCD L2 (r6 FETCH 66 MB vs 18
// ideal). gemm_direct (r9) is abandoned: no-LDS doubles request traffic.
// Attention/pack/cvt unchanged from round 8.
//
// ws layout:
//   [A] qkv_b16: 3072*3840 bf16 (23.6 MB)
//   [B] hs_b   : 3072*1280 bf16 (7.9 MB)  -- reused as attn_b after gemm1
//   [C] qkvw_b : 3840*1280 bf16 (9.8 MB)  -- reused as Qp after gemm1
//   [D] projw_b: 1280*1280 bf16 (3.3 MB)
//   [E] Kp     : 3*16*16*6144 bf16 (9.4 MB)
//   [F] Vp     : 3*16*16*6144 bf16 (9.4 MB)  (96-wide, col80 = ones)

#define S_TOT 3072
#define DIM   1280
#define NH    16
#define HD    80
#define SEG   1024
#define TDIM  3840

typedef short v8s __attribute__((ext_vector_type(8)));
typedef float v4f __attribute__((ext_vector_type(4)));

__device__ __forceinline__ short f2bf(float v) {
  __hip_bfloat16 b = __float2bfloat16(v);
  return *reinterpret_cast<short*>(&b);
}

__device__ __forceinline__ float bf2f(short s) {
  unsigned u = ((unsigned)(unsigned short)s) << 16;
  float f;
  __builtin_memcpy(&f, &u, 4);
  return f;
}

// fused fp32->bf16 for hs / qkv_w / proj_w (one launch)
#define CVT_N1 (S_TOT * DIM / 4)
#define CVT_N2 (TDIM * DIM / 4)
#define CVT_N3 (DIM * DIM / 4)
__global__ __launch_bounds__(256) void cvt3(const float* __restrict__ in1,
                                            const float* __restrict__ in2,
                                            const float* __restrict__ in3,
                                            __hip_bfloat16* __restrict__ o1,
                                            __hip_bfloat16* __restrict__ o2,
                                            __hip_bfloat16* __restrict__ o3) {
  int i = blockIdx.x * 256 + threadIdx.x;
  const float* in;
  __hip_bfloat16* out;
  if (i < CVT_N1) { in = in1; out = o1; }
  else if (i < CVT_N1 + CVT_N2) { in = in2; out = o2; i -= CVT_N1; }
  else { in = in3; out = o3; i -= CVT_N1 + CVT_N2; }
  const float4 v = ((const float4*)in)[i];
  __hip_bfloat162 p0, p1;
  p0.x = __float2bfloat16(v.x); p0.y = __float2bfloat16(v.y);
  p1.x = __float2bfloat16(v.z); p1.y = __float2bfloat16(v.w);
  __hip_bfloat162* o = (__hip_bfloat162*)(out + (size_t)i * 4);
  o[0] = p0; o[1] = p1;
}

// ---------------- gemm1: 128x128, BK=32, depth-1 reg prefetch (r6 structure),
// grid = (M/128 fastest, N/128): consecutive blocks share the B tile. ----------
__global__ __launch_bounds__(256) void gemm128_db(const __hip_bfloat16* __restrict__ A,
                                                  const __hip_bfloat16* __restrict__ B,
                                                  const float* __restrict__ bias,
                                                  __hip_bfloat16* __restrict__ C,
                                                  int M, int N, int K) {
  __shared__ __align__(16) short Abuf[2][4096];  // 16 KB
  __shared__ __align__(16) short Bbuf[2][4096];  // 16 KB
  const int tid  = threadIdx.x;
  const int wave = tid >> 6;
  const int lane = tid & 63;
  const int bm = blockIdx.x * 128;   // M fastest
  const int bn = blockIdx.y * 128;
  const int wm = (wave >> 1) * 64;
  const int wn = (wave & 1) * 64;

  const int r0 = tid & 127, kh0 = tid >> 7;
  const __hip_bfloat16* Ag0 = A + (size_t)(bm + r0) * K + kh0 * 8;
  const __hip_bfloat16* Ag1 = Ag0 + 16;  // kh0+2
  const __hip_bfloat16* Bg0 = B + (size_t)(bn + r0) * K + kh0 * 8;
  const __hip_bfloat16* Bg1 = Bg0 + 16;

  v4f acc[4][4];
  const v4f vz = {0.f, 0.f, 0.f, 0.f};
  #pragma unroll
  for (int i = 0; i < 4; ++i)
    #pragma unroll
    for (int j = 0; j < 4; ++j) acc[i][j] = vz;

  const int kh = lane >> 4;
  const int lr = lane & 15;
  const int nk = K >> 5;  // 40

  v8s a0 = *(const v8s*)Ag0, a1 = *(const v8s*)Ag1;
  v8s b0 = *(const v8s*)Bg0, b1 = *(const v8s*)Bg1;
  *(v8s*)&Abuf[0][tid * 8] = a0;  *(v8s*)&Abuf[0][(tid + 256) * 8] = a1;
  *(v8s*)&Bbuf[0][tid * 8] = b0;  *(v8s*)&Bbuf[0][(tid + 256) * 8] = b1;
  __syncthreads();

  for (int k = 0; k < nk; ++k) {
    const int cur = k & 1;
    const bool more = (k + 1 < nk);
    v8s na0, na1, nb0, nb1;
    if (more) {
      const int off = (k + 1) * 32;
      na0 = *(const v8s*)(Ag0 + off); na1 = *(const v8s*)(Ag1 + off);
      nb0 = *(const v8s*)(Bg0 + off); nb1 = *(const v8s*)(Bg1 + off);
    }
    v8s af[4], bf[4];
    #pragma unroll
    for (int i = 0; i < 4; ++i) {
      af[i] = *(const v8s*)&Abuf[cur][(kh * 128 + wm + i * 16 + lr) * 8];
      bf[i] = *(const v8s*)&Bbuf[cur][(kh * 128 + wn + i * 16 + lr) * 8];
    }
    #pragma unroll
    for (int i = 0; i < 4; ++i)
      #pragma unroll
      for (int j = 0; j < 4; ++j)
        acc[i][j] = __builtin_amdgcn_mfma_f32_16x16x32_bf16(af[i], bf[j], acc[i][j], 0, 0, 0);
    if (more) {
      *(v8s*)&Abuf[1 - cur][tid * 8] = na0;  *(v8s*)&Abuf[1 - cur][(tid + 256) * 8] = na1;
      *(v8s*)&Bbuf[1 - cur][tid * 8] = nb0;  *(v8s*)&Bbuf[1 - cur][(tid + 256) * 8] = nb1;
    }
    __syncthreads();
  }

  const int lq = lane >> 4;
  #pragma unroll
  for (int j = 0; j < 4; ++j) {
    const int col = bn + wn + j * 16 + lr;
    const float bj = bias[col];
    #pragma unroll
    for (int i = 0; i < 4; ++i) {
      const int row0 = bm + wm + i * 16 + lq * 4;
      #pragma unroll
      for (int r = 0; r < 4; ++r)
        C[(size_t)(row0 + r) * N + col] = __float2bfloat16(acc[i][j][r] + bj);
    }
  }
}

// ---------------- gemm2: 64x128, BK=32, depth-1 prefetch, swapped grid ---------
__global__ __launch_bounds__(256) void gemm2_db(const __hip_bfloat16* __restrict__ A,
                                                const __hip_bfloat16* __restrict__ B,
                                                const float* __restrict__ bias,
                                                float* __restrict__ C,
                                                int M, int N, int K) {
  __shared__ __align__(16) short Abuf[2][2048];  // 8 KB
  __shared__ __align__(16) short Bbuf[2][4096];  // 16 KB
  const int tid  = threadIdx.x;
  const int wave = tid >> 6;
  const int lane = tid & 63;
  const int quad = lane >> 4;
  const int l16  = lane & 15;
  const int bm = blockIdx.x * 64;    // M fastest
  const int bn = blockIdx.y * 128;
  const int wm = (wave & 1) * 32;
  const int wn = (wave >> 1) * 64;

  const __hip_bfloat16* Ag  = A + (size_t)(bm + (tid & 63)) * K + (tid >> 6) * 8;
  const __hip_bfloat16* Bg0 = B + (size_t)(bn + (tid & 127)) * K + (tid >> 7) * 8;
  const __hip_bfloat16* Bg1 = Bg0 + 16;

  v4f acc[2][4];
  const v4f vz = {0.f, 0.f, 0.f, 0.f};
  #pragma unroll
  for (int i = 0; i < 2; ++i)
    #pragma unroll
    for (int j = 0; j < 4; ++j) acc[i][j] = vz;

  const int nk = K >> 5;
  v8s a0 = *(const v8s*)Ag;
  v8s b0 = *(const v8s*)Bg0, b1 = *(const v8s*)Bg1;
  *(v8s*)&Abuf[0][tid * 8] = a0;
  *(v8s*)&Bbuf[0][tid * 8] = b0;  *(v8s*)&Bbuf[0][(tid + 256) * 8] = b1;
  __syncthreads();

  for (int k = 0; k < nk; ++k) {
    const int cur = k & 1;
    const bool more = (k + 1 < nk);
    v8s na0, nb0, nb1;
    if (more) {
      const int off = (k + 1) * 32;
      na0 = *(const v8s*)(Ag + off);
      nb0 = *(const v8s*)(Bg0 + off); nb1 = *(const v8s*)(Bg1 + off);
    }
    v8s af[2], bf[4];
    #pragma unroll
    for (int i = 0; i < 2; ++i)
      af[i] = *(const v8s*)&Abuf[cur][(quad * 64 + wm + i * 16 + l16) * 8];
    #pragma unroll
    for (int j = 0; j < 4; ++j)
      bf[j] = *(const v8s*)&Bbuf[cur][(quad * 128 + wn + j * 16 + l16) * 8];
    #pragma unroll
    for (int i = 0; i < 2; ++i)
      #pragma unroll
      for (int j = 0; j < 4; ++j)
        acc[i][j] = __builtin_amdgcn_mfma_f32_16x16x32_bf16(af[i], bf[j], acc[i][j], 0, 0, 0);
    if (more) {
      *(v8s*)&Abuf[1 - cur][tid * 8] = na0;
      *(v8s*)&Bbuf[1 - cur][tid * 8] = nb0;  *(v8s*)&Bbuf[1 - cur][(tid + 256) * 8] = nb1;
    }
    __syncthreads();
  }

  #pragma unroll
  for (int j = 0; j < 4; ++j) {
    const int col = bn + wn + j * 16 + l16;
    const float bj = bias[col];
    #pragma unroll
    for (int i = 0; i < 2; ++i) {
      const int row0 = bm + wm + i * 16 + quad * 4;
      #pragma unroll
      for (int r = 0; r < 4; ++r)
        C[(size_t)(row0 + r) * N + col] = acc[i][j][r] + bj;
    }
  }
}

// ---------------- merged pack kernel (unchanged) ----------------
#define QK_BLOCKS ((2 * S_TOT * 16 * 12) / 256)   // 4608
#define V_BLOCKS  ((3 * 16 * 16 * 8 * 96) / 256)  // 2304
__global__ __launch_bounds__(256) void pack_all(const __hip_bfloat16* __restrict__ qkv,
                                                const float* __restrict__ cos_,
                                                const float* __restrict__ sin_,
                                                short* __restrict__ Qp,
                                                short* __restrict__ Kp,
                                                short* __restrict__ Vp) {
  const int bid = blockIdx.x;
  if (bid < QK_BLOCKS) {
    const int idx = bid * 256 + threadIdx.x;
    const int kd = idx % 12;
    const int h  = (idx / 12) % 16;
    const int s  = (idx / 192) % S_TOT;
    const int p  = idx / (192 * S_TOT);
    const int seg = s >> 10, tb = (s >> 6) & 15, t = s & 63;
    short* out = (p ? Kp : Qp) +
                 ((size_t)(((seg * 16 + h) * 16 + tb) * 12 + kd) * 64 + t) * 8;
    short tmp[8];
    if (kd >= 10) {
      #pragma unroll
      for (int j = 0; j < 8; ++j) tmp[j] = 0;
      *(int4*)out = *(int4*)tmp;
      return;
    }
    const short* row = (const short*)qkv + (size_t)s * TDIM + p * DIM + h * HD;
    const int d0 = kd * 8;
    const v8s xm = *(const v8s*)(row + d0);
    const v8s xr = *(const v8s*)(row + d0 + ((kd < 5) ? 40 : -40));
    const float sgn = (kd < 5) ? -1.f : 1.f;
    const float scale = (p == 0) ? 0.111803398874989485f : 1.0f;
    #pragma unroll
    for (int j = 0; j < 8; ++j) {
      const int d = d0 + j;
      const float v = (bf2f(xm[j]) * cos_[s * HD + d] +
                       sgn * bf2f(xr[j]) * sin_[s * HD + d]) * scale;
      tmp[j] = f2bf(v);
    }
    *(int4*)out = *(int4*)tmp;
  } else {
    const int idx = (bid - QK_BLOCKS) * 256 + threadIdx.x;
    const int d  = idx % 96;
    const int td = (idx / 96) % 8;
    const int tb = (idx / 768) % 16;
    const int h  = (idx / (768 * 16)) % 16;
    const int seg = idx / (768 * 256);
    const int s0 = seg * SEG + tb * 64 + td * 8;
    const short* q = (const short*)qkv;
    short tmp[8];
    if (d < 80) {
      #pragma unroll
      for (int j = 0; j < 8; ++j)
        tmp[j] = q[(size_t)(s0 + j) * TDIM + 2 * DIM + h * HD + d];
    } else {
      const short fill = (d == 80) ? (short)0x3F80 : (short)0;
      #pragma unroll
      for (int j = 0; j < 8; ++j) tmp[j] = fill;
    }
    *(int4*)(Vp + (size_t)idx * 8) = *(int4*)tmp;
  }
}

// ---------------- flash MFMA attention (unchanged from round 8) ----------------
__global__ __launch_bounds__(256, 3) void attn_mfma(const short* __restrict__ Qp,
                                                    const short* __restrict__ Kp,
                                                    const short* __restrict__ Vp,
                                                    __hip_bfloat16* __restrict__ out) {
  __shared__ __align__(16) short Qs[64 * 96];     // 12 KB
  __shared__ __align__(16) short Ks[64 * 96];     // 12 KB
  __shared__ __align__(16) short Vs[64 * 96];     // 12 KB
  __shared__ __align__(16) short Ps[4][16 * 68];  // 8.5 KB, wave-private

  const int qt  = blockIdx.x;
  const int h   = blockIdx.y;
  const int seg = blockIdx.z;
  const int tid  = threadIdx.x;
  const int wave = tid >> 6;
  const int lane = tid & 63;
  const int quad = lane >> 4;
  const int l16  = lane & 15;
  const int sh16 = seg * 16 + h;

  const short* Qg = Qp + (size_t)(sh16 * 16 + qt) * 6144;
  const short* Kg = Kp + (size_t)sh16 * 16 * 6144;
  const short* Vg = Vp + (size_t)sh16 * 16 * 6144;

  v8s qr[3], kr[3], vr[3];
  #pragma unroll
  for (int it = 0; it < 3; ++it) {
    const int o = (it * 256 + tid) * 8;
    qr[it] = *(const v8s*)(Qg + o);
    kr[it] = *(const v8s*)(Kg + o);
    vr[it] = *(const v8s*)(Vg + o);
  }
  #pragma unroll
  for (int it = 0; it < 3; ++it) {
    const int o = (it * 256 + tid) * 8;
    *(v8s*)&Qs[o] = qr[it];
    *(v8s*)&Ks[o] = kr[it];
    *(v8s*)&Vs[o] = vr[it];
  }
  __syncthreads();

  v8s af[3];
  #pragma unroll
  for (int ks = 0; ks < 3; ++ks)
    af[ks] = *(const v8s*)&Qs[((ks * 4 + quad) * 64 + wave * 16 + l16) * 8];

  v4f o4[6];
  const v4f vz = {0.f, 0.f, 0.f, 0.f};
  #pragma unroll
  for (int n = 0; n < 6; ++n) o4[n] = vz;

  for (int kb = 0; kb < 16; ++kb) {
    const bool more = (kb + 1 < 16);
    if (more) {
      const size_t base = (size_t)(kb + 1) * 6144;
      #pragma unroll
      for (int it = 0; it < 3; ++it) {
        const int o = (it * 256 + tid) * 8;
        kr[it] = *(const v8s*)(Kg + base + o);
        vr[it] = *(const v8s*)(Vg + base + o);
      }
    }

    v4f s4[4];
    #pragma unroll
    for (int j = 0; j < 4; ++j) {
      s4[j] = vz;
      #pragma unroll
      for (int ks = 0; ks < 3; ++ks) {
        const v8s bf = *(const v8s*)&Ks[((ks * 4 + quad) * 64 + j * 16 + l16) * 8];
        s4[j] = __builtin_amdgcn_mfma_f32_16x16x32_bf16(af[ks], bf, s4[j], 0, 0, 0);
      }
    }

    #pragma unroll
    for (int reg = 0; reg < 4; ++reg)
      #pragma unroll
      for (int j = 0; j < 4; ++j)
        Ps[wave][(quad * 4 + reg) * 68 + j * 16 + l16] = f2bf(__expf(s4[j][reg]));

    v8s pa[2];
    #pragma unroll
    for (int kp = 0; kp < 2; ++kp)
      pa[kp] = *(const v8s*)&Ps[wave][l16 * 68 + kp * 32 + quad * 8];
    #pragma unroll
    for (int n = 0; n < 6; ++n) {
      #pragma unroll
      for (int kp = 0; kp < 2; ++kp) {
        const v8s vb = *(const v8s*)&Vs[((kp * 4 + quad) * 96 + n * 16 + l16) * 8];
        o4[n] = __builtin_amdgcn_mfma_f32_16x16x32_bf16(pa[kp], vb, o4[n], 0, 0, 0);
      }
    }

    __syncthreads();
    if (more) {
      #pragma unroll
      for (int it = 0; it < 3; ++it) {
        const int o = (it * 256 + tid) * 8;
        *(v8s*)&Ks[o] = kr[it];
        *(v8s*)&Vs[o] = vr[it];
      }
    }
    __syncthreads();
  }

  float inv[4];
  #pragma unroll
  for (int r = 0; r < 4; ++r)
    inv[r] = 1.f / __shfl(o4[5][r], quad << 4);
  const int row0 = seg * SEG + qt * 64 + wave * 16 + quad * 4;
  #pragma unroll
  for (int n = 0; n < 5; ++n) {
    const int col = h * HD + n * 16 + l16;
    #pragma unroll
    for (int r = 0; r < 4; ++r)
      out[(size_t)(row0 + r) * DIM + col] = __float2bfloat16(o4[n][r] * inv[r]);
  }
}

extern "C" void kernel_launch(void* const* d_in, const int* in_sizes, int n_in,
                              void* d_out, int out_size, void* d_ws, size_t ws_size,
                              hipStream_t stream) {
  (void)in_sizes; (void)n_in; (void)out_size; (void)ws_size;
  const float* hs     = (const float*)d_in[0];
  const float* cosp   = (const float*)d_in[1];
  const float* sinp   = (const float*)d_in[2];
  const float* qkv_w  = (const float*)d_in[3];
  const float* qkv_b  = (const float*)d_in[4];
  const float* proj_w = (const float*)d_in[5];
  const float* proj_b = (const float*)d_in[6];

  float* out_f = (float*)d_out;
  __hip_bfloat16* qkv_b16 = (__hip_bfloat16*)d_ws;                     // [A]
  __hip_bfloat16* hs_b    = qkv_b16 + (size_t)S_TOT * TDIM;            // [B]
  __hip_bfloat16* qkvw_b  = hs_b + (size_t)S_TOT * DIM;                // [C]
  __hip_bfloat16* projw_b = qkvw_b + (size_t)TDIM * DIM;               // [D]
  short* Qp = (short*)qkvw_b;                                          // alias [C]
  short* Kp = (short*)(projw_b + (size_t)DIM * DIM);                   // [E]
  short* Vp = Kp + (size_t)3 * 16 * 16 * 6144;                         // [F]
  __hip_bfloat16* attn_b = hs_b;                                       // alias [B]

  cvt3<<<(CVT_N1 + CVT_N2 + CVT_N3) / 256, 256, 0, stream>>>(
      hs, qkv_w, proj_w, hs_b, qkvw_b, projw_b);

  // grid: M fastest (x), N second (y) -> resident blocks share one B tile
  gemm128_db<<<dim3(S_TOT / 128, TDIM / 128), 256, 0, stream>>>(
      hs_b, qkvw_b, qkv_b, qkv_b16, S_TOT, TDIM, DIM);

  pack_all<<<QK_BLOCKS + V_BLOCKS, 256, 0, stream>>>(qkv_b16, cosp, sinp, Qp, Kp, Vp);

  attn_mfma<<<dim3(16, NH, 3), 256, 0, stream>>>(Qp, Kp, Vp, attn_b);

  gemm2_db<<<dim3(S_TOT / 64, DIM / 128), 256, 0, stream>>>(
      attn_b, projw_b, proj_b, out_f, S_TOT, DIM, DIM);
}